// Round 13
// baseline (455.791 us; speedup 1.0000x reference)
//
#include <hip/hip_runtime.h>
#include <hip/hip_bf16.h>
#include <math.h>

#define T_TOK 4096
#define D_EMB 768
#define DFF   3072
#define N_EXP 8
#define MAXT  72
#define CNTS  16

typedef __attribute__((ext_vector_type(8))) short bf16x8;
typedef __attribute__((ext_vector_type(4))) float f32x4;

typedef __attribute__((address_space(3))) unsigned int lds_u32_t;
typedef __attribute__((address_space(1))) unsigned int glob_u32_t;

__device__ __forceinline__ void gload16(const void* g, void* l) {
  __builtin_amdgcn_global_load_lds((const glob_u32_t*)g, (lds_u32_t*)l, 16, 0, 0);
}

__device__ __forceinline__ short f2bf(float f) {
  union { __hip_bfloat16 b; short s; } u;
  u.b = __float2bfloat16(f);
  return u.s;
}

// ---------------- zero out + counters ----------------
__global__ void zero_init_kernel(float4* __restrict__ out4, int n4, int* __restrict__ cnt) {
  int i = blockIdx.x * blockDim.x + threadIdx.x;
  if (i < N_EXP * CNTS) cnt[i] = 0;
  float4 z; z.x = z.y = z.z = z.w = 0.f;
  for (int j = i; j < n4; j += gridDim.x * blockDim.x) out4[j] = z;
}

// ---------------- x fp32 -> bf16 ----------------
__global__ void cast_x_kernel(const float4* __restrict__ in, short4* __restrict__ outp, int n4) {
  int i = blockIdx.x * blockDim.x + threadIdx.x;
  if (i >= n4) return;
  float4 v = in[i];
  short4 o;
  o.x = f2bf(v.x); o.y = f2bf(v.y); o.z = f2bf(v.z); o.w = f2bf(v.w);
  outp[i] = o;
}

// ---------------- weight transpose+cast ----------------
__global__ void transpose_cast_kernel(const float* __restrict__ in, short* __restrict__ outp,
                                      int R, int C) {
  __shared__ float tile[64][65];
  int e = blockIdx.z;
  int c0 = blockIdx.x * 64, r0 = blockIdx.y * 64;
  const float* src = in + (size_t)e * R * C;
  short* dst = outp + (size_t)e * R * C;
  int tid = threadIdx.x;
#pragma unroll
  for (int it = 0; it < 4; ++it) {
    int idx = tid + it * 256;
    int r = idx >> 4;
    int c4 = idx & 15;
    float4 v = *(const float4*)&src[(size_t)(r0 + r) * C + c0 + c4 * 4];
    tile[r][c4 * 4 + 0] = v.x; tile[r][c4 * 4 + 1] = v.y;
    tile[r][c4 * 4 + 2] = v.z; tile[r][c4 * 4 + 3] = v.w;
  }
  __syncthreads();
#pragma unroll
  for (int it = 0; it < 4; ++it) {
    int idx = tid + it * 256;
    int c = idx >> 4;
    int rr = idx & 15;
    short4 o;
    o.x = f2bf(tile[rr * 4 + 0][c]);
    o.y = f2bf(tile[rr * 4 + 1][c]);
    o.z = f2bf(tile[rr * 4 + 2][c]);
    o.w = f2bf(tile[rr * 4 + 3][c]);
    *(short4*)&dst[(size_t)(c0 + c) * R + r0 + rr * 4] = o;
  }
}

// ---------------- gate ----------------
__global__ __launch_bounds__(256)
void gate_kernel(const float* __restrict__ x, const float* __restrict__ gw,
                 int* __restrict__ cnt, int* __restrict__ tok,
                 float* __restrict__ wgt) {
  __shared__ int lcnt[N_EXP];
  __shared__ int gbase[N_EXP];
  __shared__ int le[32];
  __shared__ float lw[32];
  __shared__ int lpos[32];
  int tid = threadIdx.x, lane = tid & 63, wid = tid >> 6;
  if (tid < N_EXP) lcnt[tid] = 0;
  __syncthreads();

#pragma unroll
  for (int i = 0; i < 4; i++) {
    int t = blockIdx.x * 16 + wid * 4 + i;
    float s[N_EXP];
#pragma unroll
    for (int e = 0; e < N_EXP; e++) s[e] = 0.f;
#pragma unroll
    for (int dd = 0; dd < D_EMB / 64; dd++) {
      int d = dd * 64 + lane;
      float xv = x[(size_t)t * D_EMB + d];
#pragma unroll
      for (int e = 0; e < N_EXP; e++) s[e] += xv * gw[d * N_EXP + e];
    }
#pragma unroll
    for (int e = 0; e < N_EXP; e++) {
#pragma unroll
      for (int off = 32; off > 0; off >>= 1) s[e] += __shfl_xor(s[e], off, 64);
    }
    if (lane == 0) {
      int e0 = 0;
#pragma unroll
      for (int e = 1; e < N_EXP; e++) if (s[e] > s[e0]) e0 = e;
      int e1 = -1;
#pragma unroll
      for (int e = 0; e < N_EXP; e++) {
        if (e == e0) continue;
        if (e1 < 0 || s[e] > s[e1]) e1 = e;
      }
      float p1 = __expf(s[e1] - s[e0]);
      float inv = 1.f / (1.f + p1);
      int idx = (wid * 4 + i) * 2;
      le[idx] = e0; lw[idx] = inv;           lpos[idx] = atomicAdd(&lcnt[e0], 1);
      le[idx + 1] = e1; lw[idx + 1] = p1 * inv; lpos[idx + 1] = atomicAdd(&lcnt[e1], 1);
    }
  }
  __syncthreads();
  if (tid < N_EXP) gbase[tid] = atomicAdd(&cnt[tid * CNTS], lcnt[tid]);
  __syncthreads();
  if (tid < 32) {
    int e = le[tid];
    int t = blockIdx.x * 16 + (tid >> 1);
    int p = gbase[e] + lpos[tid];
    tok[e * T_TOK + p] = t;
    wgt[e * T_TOK + p] = lw[tid];
  }
}

// ---------------- plan ----------------
__global__ void plan_kernel(const int* __restrict__ cnt, int* __restrict__ offs,
                            int* __restrict__ tile_e, int* __restrict__ tile_rt,
                            int* __restrict__ ntiles) {
  if (threadIdx.x != 0 || blockIdx.x != 0) return;
  int o = 0, nt = 0;
  for (int e = 0; e < N_EXP; e++) {
    offs[e] = o;
    int tc = (cnt[e * CNTS] + 127) >> 7;
    for (int i = 0; i < tc; i++) { tile_e[nt] = e; tile_rt[nt] = i; nt++; }
    o += cnt[e * CNTS];
  }
  *ntiles = nt;
}

// ---------------- production grouped GEMM (r12, validated) ----------------
template<int KDIM, int NDIM, int SPLITK, int GRT, int GCT, int EPI>
__global__ __launch_bounds__(256, 4)
void moe_gemm(const short* __restrict__ A, const short* __restrict__ Bw,
              const int* __restrict__ tok, const float* __restrict__ wgt,
              const int* __restrict__ cnt, const int* __restrict__ offs,
              const int* __restrict__ tile_e, const int* __restrict__ tile_rt,
              const int* __restrict__ ntiles,
              short* __restrict__ hout, float* __restrict__ fout) {
  const int COLT = NDIM / 128;
  const int KS = KDIM / SPLITK;
  const int NKT = KS / 32;
  const int BPS = GRT * GCT;
  const int NCG = COLT / GCT;
  const int PER_SK = MAXT * COLT;

  int nwg = gridDim.x;
  int cpx = nwg >> 3;
  int logical = (blockIdx.x & 7) * cpx + (blockIdx.x >> 3);
  int sk = logical / PER_SK;
  int rem = logical % PER_SK;
  int super = rem / BPS, inner = rem % BPS;
  int band = super / NCG, cg = super % NCG;
  int tile = band * GRT + (inner % GRT);
  int ct = cg * GCT + (inner / GRT);
  if (tile >= *ntiles) return;
  int e = tile_e[tile], rt = tile_rt[tile];
  int ne = cnt[e * CNTS];
  int base = offs[e];

  __shared__ __align__(16) short As[2][128 * 32];
  __shared__ __align__(16) short Bs[2][128 * 32];

  int tid = threadIdx.x;
  int lane = tid & 63;
  int wid = tid >> 6;

  const short* aptr[2];
  const short* bptr[2];
  int lofs[2];
#pragma unroll
  for (int i = 0; i < 2; i++) {
    int seg = tid + i * 256;
    int row = seg >> 2;
    int p = seg & 3;
    int q = p ^ ((row ^ (row >> 2)) & 3);
    int r = rt * 128 + row;
    if (r >= ne) r = ne - 1;
    size_t ga = (EPI == 0) ? (size_t)tok[e * T_TOK + r] : (size_t)(base + r);
    aptr[i] = A + ga * KDIM + sk * KS + q * 8;
    bptr[i] = Bw + ((size_t)e * NDIM + ct * 128 + row) * KDIM + sk * KS + q * 8;
    lofs[i] = seg * 8;
  }

  f32x4 acc[4][4];
#pragma unroll
  for (int m = 0; m < 4; m++)
#pragma unroll
    for (int n = 0; n < 4; n++) acc[m][n] = (f32x4){0.f, 0.f, 0.f, 0.f};

  int wr = (wid >> 1) * 64, wc = (wid & 1) * 64;

#pragma unroll
  for (int i = 0; i < 2; i++) {
    gload16(aptr[i], &As[0][lofs[i]]);
    gload16(bptr[i], &Bs[0][lofs[i]]);
  }
  __syncthreads();

  int cur = 0;
  for (int kt = 0; kt < NKT; ++kt) {
    if (kt + 1 < NKT) {
      int k0 = (kt + 1) * 32;
#pragma unroll
      for (int i = 0; i < 2; i++) {
        gload16(aptr[i] + k0, &As[cur ^ 1][lofs[i]]);
        gload16(bptr[i] + k0, &Bs[cur ^ 1][lofs[i]]);
      }
    }
    int cb = lane >> 4;
    bf16x8 af[4], bv[4];
#pragma unroll
    for (int m = 0; m < 4; m++) {
      int row = wr + m * 16 + (lane & 15);
      af[m] = *(const bf16x8*)&As[cur][row * 32 + ((cb ^ ((row ^ (row >> 2)) & 3)) * 8)];
    }
#pragma unroll
    for (int n = 0; n < 4; n++) {
      int row = wc + n * 16 + (lane & 15);
      bv[n] = *(const bf16x8*)&Bs[cur][row * 32 + ((cb ^ ((row ^ (row >> 2)) & 3)) * 8)];
    }
#pragma unroll
    for (int m = 0; m < 4; m++)
#pragma unroll
      for (int n = 0; n < 4; n++)
        acc[m][n] = __builtin_amdgcn_mfma_f32_16x16x32_bf16(af[m], bv[n], acc[m][n], 0, 0, 0);
    __syncthreads();
    cur ^= 1;
  }

  int colbase = ct * 128 + wc;
#pragma unroll
  for (int m = 0; m < 4; m++) {
#pragma unroll
    for (int j = 0; j < 4; j++) {
      int rloc = rt * 128 + wr + m * 16 + ((lane >> 4) << 2) + j;
      if (rloc < ne) {
        if (EPI == 0) {
          size_t hrow = (size_t)(base + rloc) * NDIM;
#pragma unroll
          for (int n = 0; n < 4; n++) {
            float v = acc[m][n][j];
            float g = 0.5f * v * (1.0f + erff(v * 0.70710678118f));
            hout[hrow + colbase + n * 16 + (lane & 15)] = f2bf(g);
          }
        } else {
          int t = tok[e * T_TOK + rloc];
          float w = wgt[e * T_TOK + rloc];
          float* orow = fout + (size_t)t * NDIM + colbase + (lane & 15);
#pragma unroll
          for (int n = 0; n < 4; n++)
            atomicAdd(orow + n * 16, w * acc[m][n][j]);
        }
      }
    }
  }
}

// ================ ABLATION PROBES (FC shape; garbage into h, FC overwrites) ================
// abl_nostage: identical loop minus in-loop staging. tid0 ds_write defeats LDS-read CSE.
__global__ __launch_bounds__(256, 4)
void abl_nostage(const short* __restrict__ A, const short* __restrict__ Bw,
                 const int* __restrict__ tok, const int* __restrict__ cnt,
                 const int* __restrict__ offs, const int* __restrict__ tile_e,
                 const int* __restrict__ tile_rt, const int* __restrict__ ntiles,
                 short* __restrict__ hout) {
  const int KDIM = D_EMB, NDIM = DFF, NKT = 24, REPS = 4;
  int nwg = gridDim.x, cpx = nwg >> 3;
  int logical = (blockIdx.x & 7) * cpx + (blockIdx.x >> 3);
  int super = logical / 64, inner = logical % 64;
  int band = super / 3, cg = super % 3;
  int tile = band * 8 + (inner % 8);
  int ct = cg * 8 + (inner / 8);
  if (tile >= *ntiles) return;
  int e = tile_e[tile], rt = tile_rt[tile];
  int ne = cnt[e * CNTS];
  int base = offs[e];

  __shared__ __align__(16) short As[2][128 * 32];
  __shared__ __align__(16) short Bs[2][128 * 32];
  int tid = threadIdx.x, lane = tid & 63, wid = tid >> 6;

  const short* aptr[2]; const short* bptr[2]; int lofs[2];
#pragma unroll
  for (int i = 0; i < 2; i++) {
    int seg = tid + i * 256;
    int row = seg >> 2, p = seg & 3;
    int q = p ^ ((row ^ (row >> 2)) & 3);
    int r = rt * 128 + row; if (r >= ne) r = ne - 1;
    size_t ga = (size_t)tok[e * T_TOK + r];
    aptr[i] = A + ga * KDIM + q * 8;
    bptr[i] = Bw + ((size_t)e * NDIM + ct * 128 + row) * KDIM + q * 8;
    lofs[i] = seg * 8;
  }

  f32x4 acc[4][4];
#pragma unroll
  for (int m = 0; m < 4; m++)
#pragma unroll
    for (int n = 0; n < 4; n++) acc[m][n] = (f32x4){0.f, 0.f, 0.f, 0.f};
  int wr = (wid >> 1) * 64, wc = (wid & 1) * 64;

  // prologue ONLY staging: tile0 -> buf0, tile1 -> buf1
#pragma unroll
  for (int i = 0; i < 2; i++) {
    gload16(aptr[i], &As[0][lofs[i]]);      gload16(bptr[i], &Bs[0][lofs[i]]);
    gload16(aptr[i] + 32, &As[1][lofs[i]]); gload16(bptr[i] + 32, &Bs[1][lofs[i]]);
  }
  __syncthreads();

  int cur = 0;
#pragma unroll 1
  for (int kt = 0; kt < NKT * REPS; ++kt) {
    if (tid == 0) As[cur][0] ^= 1;   // force LDS re-read across barrier
    int cb = lane >> 4;
    bf16x8 af[4], bv[4];
#pragma unroll
    for (int m = 0; m < 4; m++) {
      int row = wr + m * 16 + (lane & 15);
      af[m] = *(const bf16x8*)&As[cur][row * 32 + ((cb ^ ((row ^ (row >> 2)) & 3)) * 8)];
    }
#pragma unroll
    for (int n = 0; n < 4; n++) {
      int row = wc + n * 16 + (lane & 15);
      bv[n] = *(const bf16x8*)&Bs[cur][row * 32 + ((cb ^ ((row ^ (row >> 2)) & 3)) * 8)];
    }
#pragma unroll
    for (int m = 0; m < 4; m++)
#pragma unroll
      for (int n = 0; n < 4; n++)
        acc[m][n] = __builtin_amdgcn_mfma_f32_16x16x32_bf16(af[m], bv[n], acc[m][n], 0, 0, 0);
    __syncthreads();
    cur ^= 1;
  }

  int colbase = ct * 128 + wc;
#pragma unroll
  for (int m = 0; m < 4; m++) {
#pragma unroll
    for (int j = 0; j < 4; j++) {
      int rloc = rt * 128 + wr + m * 16 + ((lane >> 4) << 2) + j;
      if (rloc < ne) {
        size_t hrow = (size_t)(base + rloc) * NDIM;
#pragma unroll
        for (int n = 0; n < 4; n++)
          hout[hrow + colbase + n * 16 + (lane & 15)] = f2bf(acc[m][n][j]);
      }
    }
  }
}

// abl_noread: staging + barriers kept; MFMA on fixed register fragments (no in-loop ds_read)
__global__ __launch_bounds__(256, 4)
void abl_noread(const short* __restrict__ A, const short* __restrict__ Bw,
                const int* __restrict__ tok, const int* __restrict__ cnt,
                const int* __restrict__ offs, const int* __restrict__ tile_e,
                const int* __restrict__ tile_rt, const int* __restrict__ ntiles,
                short* __restrict__ hout) {
  const int KDIM = D_EMB, NDIM = DFF, NKT = 24, REPS = 2;
  int nwg = gridDim.x, cpx = nwg >> 3;
  int logical = (blockIdx.x & 7) * cpx + (blockIdx.x >> 3);
  int super = logical / 64, inner = logical % 64;
  int band = super / 3, cg = super % 3;
  int tile = band * 8 + (inner % 8);
  int ct = cg * 8 + (inner / 8);
  if (tile >= *ntiles) return;
  int e = tile_e[tile], rt = tile_rt[tile];
  int ne = cnt[e * CNTS];
  int base = offs[e];

  __shared__ __align__(16) short As[2][128 * 32];
  __shared__ __align__(16) short Bs[2][128 * 32];
  int tid = threadIdx.x, lane = tid & 63, wid = tid >> 6;

  const short* aptr[2]; const short* bptr[2]; int lofs[2];
#pragma unroll
  for (int i = 0; i < 2; i++) {
    int seg = tid + i * 256;
    int row = seg >> 2, p = seg & 3;
    int q = p ^ ((row ^ (row >> 2)) & 3);
    int r = rt * 128 + row; if (r >= ne) r = ne - 1;
    size_t ga = (size_t)tok[e * T_TOK + r];
    aptr[i] = A + ga * KDIM + q * 8;
    bptr[i] = Bw + ((size_t)e * NDIM + ct * 128 + row) * KDIM + q * 8;
    lofs[i] = seg * 8;
  }

  f32x4 acc[4][4];
#pragma unroll
  for (int m = 0; m < 4; m++)
#pragma unroll
    for (int n = 0; n < 4; n++) acc[m][n] = (f32x4){0.f, 0.f, 0.f, 0.f};
  int wr = (wid >> 1) * 64, wc = (wid & 1) * 64;

  bf16x8 af[4], bv[4];
#pragma unroll
  for (int m = 0; m < 4; m++)
#pragma unroll
    for (int v8 = 0; v8 < 8; v8++) { af[m][v8] = (short)(lane + m); bv[m][v8] = (short)(lane - m); }

#pragma unroll
  for (int i = 0; i < 2; i++) {
    gload16(aptr[i], &As[0][lofs[i]]);
    gload16(bptr[i], &Bs[0][lofs[i]]);
  }
  __syncthreads();

  int cur = 0;
#pragma unroll 1
  for (int kt = 0; kt < NKT * REPS; ++kt) {
    if (kt + 1 < NKT * REPS) {
      int k0 = (((kt + 1) % NKT)) * 32;
#pragma unroll
      for (int i = 0; i < 2; i++) {
        gload16(aptr[i] + k0, &As[cur ^ 1][lofs[i]]);
        gload16(bptr[i] + k0, &Bs[cur ^ 1][lofs[i]]);
      }
    }
#pragma unroll
    for (int m = 0; m < 4; m++)
#pragma unroll
      for (int n = 0; n < 4; n++)
        acc[m][n] = __builtin_amdgcn_mfma_f32_16x16x32_bf16(af[m], bv[n], acc[m][n], 0, 0, 0);
    __syncthreads();
    cur ^= 1;
  }

  int colbase = ct * 128 + wc;
#pragma unroll
  for (int m = 0; m < 4; m++) {
#pragma unroll
    for (int j = 0; j < 4; j++) {
      int rloc = rt * 128 + wr + m * 16 + ((lane >> 4) << 2) + j;
      if (rloc < ne) {
        size_t hrow = (size_t)(base + rloc) * NDIM;
#pragma unroll
        for (int n = 0; n < 4; n++)
          hout[hrow + colbase + n * 16 + (lane & 15)] = f2bf(acc[m][n][j]);
      }
    }
  }
}

extern "C" void kernel_launch(void* const* d_in, const int* in_sizes, int n_in,
                              void* d_out, int out_size, void* d_ws, size_t ws_size,
                              hipStream_t stream) {
  const float* x   = (const float*)d_in[0];
  const float* gw  = (const float*)d_in[1];
  const float* wfc = (const float*)d_in[2];
  const float* wpj = (const float*)d_in[3];
  float* out = (float*)d_out;

  char* ws = (char*)d_ws;
  const size_t SZ_XB = (size_t)T_TOK * D_EMB * 2;
  const size_t SZ_W  = (size_t)N_EXP * D_EMB * DFF * 2;
  const size_t SZ_H  = (size_t)2 * T_TOK * DFF * 2;
  short* xb   = (short*)(ws);
  short* wfcT = (short*)(ws + SZ_XB);
  short* wpjT = (short*)(ws + SZ_XB + SZ_W);
  short* h    = (short*)(ws + SZ_XB + 2 * SZ_W);
  char* p2    = ws + SZ_XB + 2 * SZ_W + SZ_H;
  int*   tok  = (int*)(p2);
  float* wgt  = (float*)(p2 + (size_t)N_EXP * T_TOK * 4);
  char* p3    = p2 + (size_t)N_EXP * T_TOK * 8;
  int*   cnt     = (int*)(p3);
  int*   offs    = (int*)(p3 + 1024);
  int*   tile_e  = (int*)(p3 + 1024 + 64);
  int*   tile_rt = (int*)(p3 + 1024 + 64 + 512);
  int*   ntiles  = (int*)(p3 + 1024 + 64 + 1024);

  int n4 = out_size / 4;
  zero_init_kernel<<<2048, 256, 0, stream>>>((float4*)out, n4, cnt);
  cast_x_kernel<<<(T_TOK * D_EMB / 4 + 255) / 256, 256, 0, stream>>>(
      (const float4*)x, (short4*)xb, T_TOK * D_EMB / 4);
  transpose_cast_kernel<<<dim3(DFF / 64, D_EMB / 64, N_EXP), 256, 0, stream>>>(wfc, wfcT, D_EMB, DFF);
  transpose_cast_kernel<<<dim3(D_EMB / 64, DFF / 64, N_EXP), 256, 0, stream>>>(wpj, wpjT, DFF, D_EMB);
  gate_kernel<<<T_TOK / 16, 256, 0, stream>>>(x, gw, cnt, tok, wgt);
  plan_kernel<<<1, 1, 0, stream>>>(cnt, offs, tile_e, tile_rt, ntiles);

  // ---- ablation probes (write garbage into h; FC fully overwrites h afterwards) ----
  abl_nostage<<<MAXT * (DFF / 128), 256, 0, stream>>>(
      xb, wfcT, tok, cnt, offs, tile_e, tile_rt, ntiles, h);
  abl_noread<<<MAXT * (DFF / 128), 256, 0, stream>>>(
      xb, wfcT, tok, cnt, offs, tile_e, tile_rt, ntiles, h);

  // ---- production ----
  moe_gemm<D_EMB, DFF, 1, 8, 8, 0><<<MAXT * (DFF / 128), 256, 0, stream>>>(
      xb, wfcT, tok, wgt, cnt, offs, tile_e, tile_rt, ntiles, h, nullptr);
  moe_gemm<DFF, D_EMB, 2, 8, 6, 1><<<2 * MAXT * (D_EMB / 128), 256, 0, stream>>>(
      h, wpjT, tok, wgt, cnt, offs, tile_e, tile_rt, ntiles, nullptr, out);
}

// Round 14
// 219.881 us; speedup vs baseline: 2.0729x; 2.0729x over previous
//
#include <hip/hip_runtime.h>
#include <hip/hip_bf16.h>
#include <math.h>

#define T_TOK 4096
#define D_EMB 768
#define DFF   3072
#define N_EXP 8
#define MAXT  72
#define CNTS  16

typedef __attribute__((ext_vector_type(8))) short bf16x8;
typedef __attribute__((ext_vector_type(4))) float f32x4;

typedef __attribute__((address_space(3))) unsigned int lds_u32_t;
typedef __attribute__((address_space(1))) unsigned int glob_u32_t;

__device__ __forceinline__ void gload16(const void* g, void* l) {
  __builtin_amdgcn_global_load_lds((const glob_u32_t*)g, (lds_u32_t*)l, 16, 0, 0);
}

__device__ __forceinline__ short f2bf(float f) {
  union { __hip_bfloat16 b; short s; } u;
  u.b = __float2bfloat16(f);
  return u.s;
}

// tanh-form GELU (max |err| vs exact erf-GELU ~3e-4, far below 0.056 threshold; validated r9)
__device__ __forceinline__ float gelu_f(float v) {
  float u = 0.7978845608f * v * (1.0f + 0.044715f * v * v);
  float a = fabsf(u);
  float em = __expf(-2.0f * a);
  float th = (1.0f - em) / (1.0f + em);
  th = (u < 0.0f) ? -th : th;
  return 0.5f * v * (1.0f + th);
}

__device__ __forceinline__ int swz(int row) { return (row ^ (row >> 2)) & 3; }

// ---------------- zero out + counters ----------------
__global__ void zero_init_kernel(float4* __restrict__ out4, int n4, int* __restrict__ cnt) {
  int i = blockIdx.x * blockDim.x + threadIdx.x;
  if (i < N_EXP * CNTS) cnt[i] = 0;
  float4 z; z.x = z.y = z.z = z.w = 0.f;
  for (int j = i; j < n4; j += gridDim.x * blockDim.x) out4[j] = z;
}

// ---------------- weight -> staging-slab transform ----------------
// src: [e][Kt][Nt] f32.  dst slab: [((e*NCT + ct)*NKTall + kt)*4096 + seg*8 + j] bf16
// value = src[e][kt*32 + q*8 + j][ct*128 + row], row=seg>>2, q=(seg&3)^swz(row).
// A wave staging slab[seg*8..] reads 1KB CONTIGUOUS -> 128B-line txns.
__global__ __launch_bounds__(256)
void slab_weights(const float* __restrict__ src, short* __restrict__ dst,
                  int Kt, int Nt, int NCT, int NKTall) {
  __shared__ float t32[32][132];
  int ct = blockIdx.x, kt = blockIdx.y, e = blockIdx.z;
  const float* s = src + ((size_t)e * Kt + kt * 32) * Nt + ct * 128;
  int tid = threadIdx.x;
#pragma unroll
  for (int p4 = 0; p4 < 4; p4++) {
    int idx = tid + p4 * 256;          // 0..1023 over 32 rows x 32 float4
    int kl = idx >> 5, c4 = idx & 31;
    float4 v = *(const float4*)&s[(size_t)kl * Nt + c4 * 4];
    t32[kl][c4 * 4 + 0] = v.x; t32[kl][c4 * 4 + 1] = v.y;
    t32[kl][c4 * 4 + 2] = v.z; t32[kl][c4 * 4 + 3] = v.w;
  }
  __syncthreads();
  short* d = dst + (((size_t)e * NCT + ct) * NKTall + kt) * 4096;
#pragma unroll
  for (int i = 0; i < 2; i++) {
    int seg = tid + i * 256;
    int row = seg >> 2, p = seg & 3;
    int q = p ^ swz(row);
    union { short sv[8]; uint4 u; } o;
#pragma unroll
    for (int j = 0; j < 8; j++) o.sv[j] = f2bf(t32[q * 8 + j][row]);
    *(uint4*)&d[(size_t)seg * 8] = o.u;
  }
}

// ---------------- gate: 16 tokens/block, LDS-aggregated routing ----------------
__global__ __launch_bounds__(256)
void gate_kernel(const float* __restrict__ x, const float* __restrict__ gw,
                 int* __restrict__ cnt, int* __restrict__ tok,
                 float* __restrict__ wgt) {
  __shared__ int lcnt[N_EXP];
  __shared__ int gbase[N_EXP];
  __shared__ int le[32];
  __shared__ float lw[32];
  __shared__ int lpos[32];
  int tid = threadIdx.x, lane = tid & 63, wid = tid >> 6;
  if (tid < N_EXP) lcnt[tid] = 0;
  __syncthreads();

#pragma unroll
  for (int i = 0; i < 4; i++) {
    int t = blockIdx.x * 16 + wid * 4 + i;
    float s[N_EXP];
#pragma unroll
    for (int e = 0; e < N_EXP; e++) s[e] = 0.f;
#pragma unroll
    for (int dd = 0; dd < D_EMB / 64; dd++) {
      int d = dd * 64 + lane;
      float xv = x[(size_t)t * D_EMB + d];
#pragma unroll
      for (int e = 0; e < N_EXP; e++) s[e] += xv * gw[d * N_EXP + e];
    }
#pragma unroll
    for (int e = 0; e < N_EXP; e++) {
#pragma unroll
      for (int off = 32; off > 0; off >>= 1) s[e] += __shfl_xor(s[e], off, 64);
    }
    if (lane == 0) {
      int e0 = 0;
#pragma unroll
      for (int e = 1; e < N_EXP; e++) if (s[e] > s[e0]) e0 = e;
      int e1 = -1;
#pragma unroll
      for (int e = 0; e < N_EXP; e++) {
        if (e == e0) continue;
        if (e1 < 0 || s[e] > s[e1]) e1 = e;
      }
      float p1 = __expf(s[e1] - s[e0]);
      float inv = 1.f / (1.f + p1);
      int idx = (wid * 4 + i) * 2;
      le[idx] = e0; lw[idx] = inv;           lpos[idx] = atomicAdd(&lcnt[e0], 1);
      le[idx + 1] = e1; lw[idx + 1] = p1 * inv; lpos[idx + 1] = atomicAdd(&lcnt[e1], 1);
    }
  }
  __syncthreads();
  if (tid < N_EXP) gbase[tid] = atomicAdd(&cnt[tid * CNTS], lcnt[tid]);
  __syncthreads();
  if (tid < 32) {
    int e = le[tid];
    int t = blockIdx.x * 16 + (tid >> 1);
    int p = gbase[e] + lpos[tid];
    tok[e * T_TOK + p] = t;
    wgt[e * T_TOK + p] = lw[tid];
  }
}

// ---------------- plan ----------------
__global__ void plan_kernel(const int* __restrict__ cnt, int* __restrict__ offs,
                            int* __restrict__ tile_e, int* __restrict__ tile_rt,
                            int* __restrict__ ntiles) {
  if (threadIdx.x != 0 || blockIdx.x != 0) return;
  int o = 0, nt = 0;
  for (int e = 0; e < N_EXP; e++) {
    offs[e] = o;
    int tc = (cnt[e * CNTS] + 127) >> 7;
    for (int i = 0; i < tc; i++) { tile_e[nt] = e; tile_rt[nt] = i; nt++; }
    o += cnt[e * CNTS];
  }
  *ntiles = nt;
}

// ---------------- A-slab gather (fused f32->bf16 cast): slab[tile][kt][seg] ----------------
// value = x[tok[e][rt*128+row]][kt*32 + q*8 + j]; pays the token-gather ONCE.
__global__ __launch_bounds__(256)
void gatherA_kernel(const float* __restrict__ x, const int* __restrict__ tok,
                    const int* __restrict__ cnt, const int* __restrict__ offs,
                    const int* __restrict__ tile_e, const int* __restrict__ tile_rt,
                    const int* __restrict__ ntiles, short* __restrict__ aslab) {
  int tile = blockIdx.x, kt = blockIdx.y;
  if (tile >= *ntiles) return;
  int e = tile_e[tile], rt = tile_rt[tile];
  int ne = cnt[e * CNTS];
  int tid = threadIdx.x;
  short* d = aslab + ((size_t)tile * 24 + kt) * 4096;
#pragma unroll
  for (int i = 0; i < 2; i++) {
    int seg = tid + i * 256;
    int row = seg >> 2, p = seg & 3;
    int q = p ^ swz(row);
    int r = rt * 128 + row; if (r >= ne) r = ne - 1;
    int t = tok[e * T_TOK + r];
    const float* src = x + (size_t)t * D_EMB + kt * 32 + q * 8;
    union { short sv[8]; uint4 u; } o;
#pragma unroll
    for (int j = 0; j < 8; j++) o.sv[j] = f2bf(src[j]);
    *(uint4*)&d[(size_t)seg * 8] = o.u;
  }
}

// ---------------- grouped GEMM, 128x128, BK=32, dbuf gload_lds, slab staging ----------------
// EPI=0 (FC): A from slab (contiguous 1KB/wave), B from slab.  stride/kt = 4096 shorts.
// EPI=1 (PROJ): A from h rows (sequential, stride/kt = 32), B from slab.
// K-loop/read-side byte-identical to validated r12.
template<int KDIM, int NDIM, int SPLITK, int GRT, int GCT, int EPI>
__global__ __launch_bounds__(256, 4)
void moe_gemm(const short* __restrict__ Aop, const short* __restrict__ Bslab,
              const int* __restrict__ tok, const float* __restrict__ wgt,
              const int* __restrict__ cnt, const int* __restrict__ offs,
              const int* __restrict__ tile_e, const int* __restrict__ tile_rt,
              const int* __restrict__ ntiles,
              short* __restrict__ hout, float* __restrict__ fout) {
  const int COLT = NDIM / 128;
  const int KS = KDIM / SPLITK;
  const int NKT = KS / 32;
  const int NKTALL = KDIM / 32;
  const int BPS = GRT * GCT;
  const int NCG = COLT / GCT;
  const int PER_SK = MAXT * COLT;

  int nwg = gridDim.x;
  int cpx = nwg >> 3;
  int logical = (blockIdx.x & 7) * cpx + (blockIdx.x >> 3);
  int sk = logical / PER_SK;
  int rem = logical % PER_SK;
  int super = rem / BPS, inner = rem % BPS;
  int band = super / NCG, cg = super % NCG;
  int tile = band * GRT + (inner % GRT);
  int ct = cg * GCT + (inner / GRT);
  if (tile >= *ntiles) return;
  int e = tile_e[tile], rt = tile_rt[tile];
  int ne = cnt[e * CNTS];
  int base = offs[e];

  __shared__ __align__(16) short As[2][128 * 32];
  __shared__ __align__(16) short Bs[2][128 * 32];

  int tid = threadIdx.x;
  int lane = tid & 63;
  int wid = tid >> 6;

  const int AKT = (EPI == 0) ? 4096 : 32;   // per-k-step stride (shorts)
  const short* aptr[2];
  const short* bptr[2];
  int lofs[2];
#pragma unroll
  for (int i = 0; i < 2; i++) {
    int seg = tid + i * 256;
    int row = seg >> 2, p = seg & 3;
    int q = p ^ swz(row);
    if (EPI == 0) {
      aptr[i] = Aop + ((size_t)tile * 24) * 4096 + seg * 8;
    } else {
      int r = rt * 128 + row; if (r >= ne) r = ne - 1;
      aptr[i] = Aop + (size_t)(base + r) * KDIM + sk * KS + q * 8;
    }
    bptr[i] = Bslab + (((size_t)e * COLT + ct) * NKTALL + sk * NKT) * 4096 + seg * 8;
    lofs[i] = seg * 8;
  }

  f32x4 acc[4][4];
#pragma unroll
  for (int m = 0; m < 4; m++)
#pragma unroll
    for (int n = 0; n < 4; n++) acc[m][n] = (f32x4){0.f, 0.f, 0.f, 0.f};

  int wr = (wid >> 1) * 64, wc = (wid & 1) * 64;

#pragma unroll
  for (int i = 0; i < 2; i++) {
    gload16(aptr[i], &As[0][lofs[i]]);
    gload16(bptr[i], &Bs[0][lofs[i]]);
  }
  __syncthreads();

  int cur = 0;
  for (int kt = 0; kt < NKT; ++kt) {
    if (kt + 1 < NKT) {
#pragma unroll
      for (int i = 0; i < 2; i++) {
        gload16(aptr[i] + (size_t)(kt + 1) * AKT, &As[cur ^ 1][lofs[i]]);
        gload16(bptr[i] + (size_t)(kt + 1) * 4096, &Bs[cur ^ 1][lofs[i]]);
      }
    }
    int cb = lane >> 4;
    bf16x8 af[4], bv[4];
#pragma unroll
    for (int m = 0; m < 4; m++) {
      int row = wr + m * 16 + (lane & 15);
      af[m] = *(const bf16x8*)&As[cur][row * 32 + ((cb ^ swz(row)) * 8)];
    }
#pragma unroll
    for (int n = 0; n < 4; n++) {
      int row = wc + n * 16 + (lane & 15);
      bv[n] = *(const bf16x8*)&Bs[cur][row * 32 + ((cb ^ swz(row)) * 8)];
    }
#pragma unroll
    for (int m = 0; m < 4; m++)
#pragma unroll
      for (int n = 0; n < 4; n++)
        acc[m][n] = __builtin_amdgcn_mfma_f32_16x16x32_bf16(af[m], bv[n], acc[m][n], 0, 0, 0);
    __syncthreads();
    cur ^= 1;
  }

  int colbase = ct * 128 + wc;
#pragma unroll
  for (int m = 0; m < 4; m++) {
#pragma unroll
    for (int j = 0; j < 4; j++) {
      int rloc = rt * 128 + wr + m * 16 + ((lane >> 4) << 2) + j;
      if (rloc < ne) {
        if (EPI == 0) {
          size_t hrow = (size_t)(base + rloc) * NDIM;
#pragma unroll
          for (int n = 0; n < 4; n++)
            hout[hrow + colbase + n * 16 + (lane & 15)] = f2bf(gelu_f(acc[m][n][j]));
        } else {
          int t = tok[e * T_TOK + rloc];
          float w = wgt[e * T_TOK + rloc];
          float* orow = fout + (size_t)t * NDIM + colbase + (lane & 15);
#pragma unroll
          for (int n = 0; n < 4; n++)
            atomicAdd(orow + n * 16, w * acc[m][n][j]);
        }
      }
    }
  }
}

extern "C" void kernel_launch(void* const* d_in, const int* in_sizes, int n_in,
                              void* d_out, int out_size, void* d_ws, size_t ws_size,
                              hipStream_t stream) {
  const float* x   = (const float*)d_in[0];
  const float* gw  = (const float*)d_in[1];
  const float* wfc = (const float*)d_in[2];
  const float* wpj = (const float*)d_in[3];
  float* out = (float*)d_out;

  char* ws = (char*)d_ws;
  const size_t SZ_ASLAB = (size_t)MAXT * 24 * 4096 * 2;        // 14,155,776
  const size_t SZ_BFC   = (size_t)N_EXP * 24 * 24 * 4096 * 2;  // 37,748,736
  const size_t SZ_BPJ   = (size_t)N_EXP * 6 * 96 * 4096 * 2;   // 37,748,736
  const size_t SZ_H     = (size_t)2 * T_TOK * DFF * 2;         // 50,331,648
  short* aslab = (short*)(ws);
  short* bfc   = (short*)(ws + SZ_ASLAB);
  short* bpj   = (short*)(ws + SZ_ASLAB + SZ_BFC);
  short* h     = (short*)(ws + SZ_ASLAB + SZ_BFC + SZ_BPJ);
  char* p2     = ws + SZ_ASLAB + SZ_BFC + SZ_BPJ + SZ_H;
  int*   tok  = (int*)(p2);
  float* wgt  = (float*)(p2 + (size_t)N_EXP * T_TOK * 4);
  char* p3    = p2 + (size_t)N_EXP * T_TOK * 8;
  int*   cnt     = (int*)(p3);
  int*   offs    = (int*)(p3 + 1024);
  int*   tile_e  = (int*)(p3 + 1024 + 64);
  int*   tile_rt = (int*)(p3 + 1024 + 64 + 512);
  int*   ntiles  = (int*)(p3 + 1024 + 64 + 1024);

  int n4 = out_size / 4;
  zero_init_kernel<<<2048, 256, 0, stream>>>((float4*)out, n4, cnt);
  // weight slabs (independent of routing)
  slab_weights<<<dim3(24, 24, N_EXP), 256, 0, stream>>>(wfc, bfc, D_EMB, DFF, 24, 24);
  slab_weights<<<dim3(6, 96, N_EXP), 256, 0, stream>>>(wpj, bpj, DFF, D_EMB, 6, 96);
  gate_kernel<<<T_TOK / 16, 256, 0, stream>>>(x, gw, cnt, tok, wgt);
  plan_kernel<<<1, 1, 0, stream>>>(cnt, offs, tile_e, tile_rt, ntiles);
  gatherA_kernel<<<dim3(MAXT, 24), 256, 0, stream>>>(x, tok, cnt, offs, tile_e, tile_rt, ntiles, aslab);
  // FC: K=768 (NKT=24), N=3072, supertile 8x8. grid = 72*24 = 1728 (%8==0)
  moe_gemm<D_EMB, DFF, 1, 8, 8, 0><<<MAXT * (DFF / 128), 256, 0, stream>>>(
      aslab, bfc, tok, wgt, cnt, offs, tile_e, tile_rt, ntiles, h, nullptr);
  // PROJ: K=3072 split 2 (NKT=48), N=768, supertile 8x6. grid = 2*72*6 = 864 (%8==0)
  moe_gemm<DFF, D_EMB, 2, 8, 6, 1><<<2 * MAXT * (D_EMB / 128), 256, 0, stream>>>(
      h, bpj, tok, wgt, cnt, offs, tile_e, tile_rt, ntiles, nullptr, out);
}